// Round 4
// baseline (495.504 us; speedup 1.0000x reference)
//
#include <hip/hip_runtime.h>
#include <stdint.h>

#define BK 32

typedef __attribute__((ext_vector_type(8))) short bf16x8;
typedef __attribute__((ext_vector_type(4))) float f32x4;

__device__ __forceinline__ unsigned short f2bf(float f) {
  unsigned int u = __builtin_bit_cast(unsigned int, f);
  u += 0x7fffu + ((u >> 16) & 1u);
  return (unsigned short)(u >> 16);
}
__device__ __forceinline__ float bf2f(unsigned short h) {
  unsigned int u = ((unsigned int)h) << 16;
  return __builtin_bit_cast(float, u);
}

__device__ __forceinline__ void gll16(const void* g, void* l) {
  __builtin_amdgcn_global_load_lds(
      (const __attribute__((address_space(1))) unsigned int*)g,
      (__attribute__((address_space(3))) unsigned int*)l, 16, 0, 0);
}

// ---------------------------------------------------------------------------
// bt-GEMM: C[M,N] = scale * (A[M,K] . B[N,K]^T) + bias
// BIASMODE: 0 = none, 1 = bias[col], 2 = bias[row]
// F32OUT:   0 = bf16 output, 1 = fp32 output (d_out is the reference's fp32)
// m97 structure: 128x128 tile, BK=32, 4 waves (2x2), 4x4 16x16x32 frags,
// global_load_lds(16B) staging, 2 barriers per K-step.
// ---------------------------------------------------------------------------
template <int BIASMODE, int F32OUT>
__global__ __launch_bounds__(256) void bt_gemm(
    const unsigned short* __restrict__ A, const unsigned short* __restrict__ B,
    const float* __restrict__ bias, void* __restrict__ Cv,
    int M, int N, int K, int lda, int ldb, int ldc,
    long batchA, long batchB, long batchC, float scale) {
  __shared__ __align__(16) unsigned short As[128 * BK];
  __shared__ __align__(16) unsigned short Bs[128 * BK];

  const int z = blockIdx.z;
  A += (long)z * batchA;
  B += (long)z * batchB;

  const int tid = threadIdx.x;
  const int lane = tid & 63;
  const int wid = tid >> 6;
  const int wr = wid >> 1, wc = wid & 1;
  const int bm0 = blockIdx.y * 128;
  const int bn0 = blockIdx.x * 128;

  f32x4 zero = {0.f, 0.f, 0.f, 0.f};
  f32x4 acc[4][4];
#pragma unroll
  for (int m = 0; m < 4; m++)
#pragma unroll
    for (int n = 0; n < 4; n++) acc[m][n] = zero;

  const int nk = K / BK;
  for (int kt = 0; kt < nk; ++kt) {
    const int kk = kt * BK;
#pragma unroll
    for (int i = 0; i < 2; i++) {
      int c = tid + i * 256;  // 16B chunk id; lanes contiguous within wave
      int row = c >> 2, sub = c & 3;
      gll16(A + (size_t)(bm0 + row) * lda + kk + sub * 8, (void*)(As + c * 8));
      gll16(B + (size_t)(bn0 + row) * ldb + kk + sub * 8, (void*)(Bs + c * 8));
    }
    __syncthreads();  // drains vmcnt -> LDS tiles ready

    const int kq = (lane >> 4) * 8;
    bf16x8 af[4], bfr[4];
#pragma unroll
    for (int m = 0; m < 4; m++) {
      int r = wr * 64 + m * 16 + (lane & 15);
      af[m] = *(const bf16x8*)&As[r * BK + kq];
    }
#pragma unroll
    for (int n = 0; n < 4; n++) {
      int cidx = wc * 64 + n * 16 + (lane & 15);
      bfr[n] = *(const bf16x8*)&Bs[cidx * BK + kq];
    }
#pragma unroll
    for (int m = 0; m < 4; m++)
#pragma unroll
      for (int n = 0; n < 4; n++)
        acc[m][n] = __builtin_amdgcn_mfma_f32_16x16x32_bf16(af[m], bfr[n],
                                                            acc[m][n], 0, 0, 0);
    __syncthreads();  // protect LDS before next staging
  }

  // epilogue: C/D layout col=lane&15, row=(lane>>4)*4+j  [m89-verified]
  float* Cf = (float*)Cv + (F32OUT ? (long)z * batchC : 0);
  unsigned short* Cb = (unsigned short*)Cv + (F32OUT ? 0 : (long)z * batchC);
#pragma unroll
  for (int m = 0; m < 4; m++) {
    int row0 = bm0 + wr * 64 + m * 16 + ((lane >> 4) << 2);
#pragma unroll
    for (int n = 0; n < 4; n++) {
      int col = bn0 + wc * 64 + n * 16 + (lane & 15);
      f32x4 v = acc[m][n];
      float bc = (BIASMODE == 1) ? bias[col] : 0.0f;
#pragma unroll
      for (int j = 0; j < 4; j++) {
        float bj = (BIASMODE == 2) ? bias[row0 + j] : bc;
        float r = v[j] * scale + bj;
        if (F32OUT)
          Cf[(size_t)(row0 + j) * ldc + col] = r;
        else
          Cb[(size_t)(row0 + j) * ldc + col] = f2bf(r);
      }
    }
  }
}

// ---------------------------------------------------------------------------
// fp32 -> bf16 bulk convert (float4 in, 8B out)
// ---------------------------------------------------------------------------
__global__ __launch_bounds__(256) void cvt_kernel(const float* __restrict__ in,
                                                  unsigned short* __restrict__ out,
                                                  long n4) {
  long i = (long)blockIdx.x * blockDim.x + threadIdx.x;
  long stride = (long)gridDim.x * blockDim.x;
  for (; i < n4; i += stride) {
    float4 f = ((const float4*)in)[i];
    uint2 w;
    w.x = (unsigned int)f2bf(f.x) | ((unsigned int)f2bf(f.y) << 16);
    w.y = (unsigned int)f2bf(f.z) | ((unsigned int)f2bf(f.w) << 16);
    ((uint2*)out)[i] = w;
  }
}

// ---------------------------------------------------------------------------
// W [1024,1024] fp32 -> Wt [1024,1024] bf16 transposed (LDS tiled)
// ---------------------------------------------------------------------------
__global__ __launch_bounds__(1024) void transposeW_kernel(
    const float* __restrict__ W, unsigned short* __restrict__ Wt) {
  __shared__ float t[32][33];
  int x = threadIdx.x, y = threadIdx.y;
  int d = blockIdx.y * 32 + y, n = blockIdx.x * 32 + x;
  t[y][x] = W[(size_t)d * 1024 + n];
  __syncthreads();
  int nn = blockIdx.x * 32 + y, dd = blockIdx.y * 32 + x;
  Wt[(size_t)nn * 1024 + dd] = f2bf(t[x][y]);
}

// ---------------------------------------------------------------------------
// In-place row softmax over 2048 bf16. One 256-thread block per row.
// ---------------------------------------------------------------------------
__global__ __launch_bounds__(256) void softmax_kernel(unsigned short* __restrict__ SP) {
  const int row = blockIdx.x;
  unsigned short* rp = SP + (size_t)row * 2048;
  const int tid = threadIdx.x;
  const int wid = tid >> 6, lane = tid & 63;

  uint4 u = ((const uint4*)rp)[tid];  // 8 bf16
  float xv[8];
  xv[0] = bf2f(u.x & 0xffff); xv[1] = bf2f(u.x >> 16);
  xv[2] = bf2f(u.y & 0xffff); xv[3] = bf2f(u.y >> 16);
  xv[4] = bf2f(u.z & 0xffff); xv[5] = bf2f(u.z >> 16);
  xv[6] = bf2f(u.w & 0xffff); xv[7] = bf2f(u.w >> 16);

  float m = xv[0];
#pragma unroll
  for (int j = 1; j < 8; j++) m = fmaxf(m, xv[j]);
#pragma unroll
  for (int off = 32; off >= 1; off >>= 1) m = fmaxf(m, __shfl_xor(m, off));

  __shared__ float redm[4];
  __shared__ float reds[4];
  if (lane == 0) redm[wid] = m;
  __syncthreads();
  m = fmaxf(fmaxf(redm[0], redm[1]), fmaxf(redm[2], redm[3]));

  float p[8], s = 0.f;
#pragma unroll
  for (int j = 0; j < 8; j++) {
    p[j] = __expf(xv[j] - m);
    s += p[j];
  }
#pragma unroll
  for (int off = 32; off >= 1; off >>= 1) s += __shfl_xor(s, off);
  if (lane == 0) reds[wid] = s;
  __syncthreads();
  float inv = 1.0f / (reds[0] + reds[1] + reds[2] + reds[3]);

  uint4 o;
  o.x = (unsigned int)f2bf(p[0] * inv) | ((unsigned int)f2bf(p[1] * inv) << 16);
  o.y = (unsigned int)f2bf(p[2] * inv) | ((unsigned int)f2bf(p[3] * inv) << 16);
  o.z = (unsigned int)f2bf(p[4] * inv) | ((unsigned int)f2bf(p[5] * inv) << 16);
  o.w = (unsigned int)f2bf(p[6] * inv) | ((unsigned int)f2bf(p[7] * inv) << 16);
  ((uint4*)rp)[tid] = o;
}

// ---------------------------------------------------------------------------
extern "C" void kernel_launch(void* const* d_in, const int* in_sizes, int n_in,
                              void* d_out, int out_size, void* d_ws, size_t ws_size,
                              hipStream_t stream) {
  const float* x = (const float*)d_in[0];
  const float* Wq = (const float*)d_in[1];
  const float* bq = (const float*)d_in[2];
  const float* Wk = (const float*)d_in[3];
  const float* bk = (const float*)d_in[4];
  const float* Wv = (const float*)d_in[5];
  const float* bv = (const float*)d_in[6];
  float* out = (float*)d_out;  // fp32! (reference output dtype)

  // ws layout (70 MB):
  //   [ 0,16) xb  : x bf16 [4][2048][1024]      (dead after projections)
  //   [16,32) Kb  : K bf16
  //   [32,48) Vt  : V^T bf16 [4][1024][2048]
  //   [48,64) Qb  : Q bf16
  //   [64,70) Wt q/k/v bf16 transposed
  //   [ 0, 8) SPb : per-batch scores [2048][2048] bf16 — overlays dead xb
  char* ws = (char*)d_ws;
  unsigned short* xb = (unsigned short*)ws;
  unsigned short* Kb = (unsigned short*)(ws + (16L << 20));
  unsigned short* Vt = (unsigned short*)(ws + (32L << 20));
  unsigned short* Qb = (unsigned short*)(ws + (48L << 20));
  unsigned short* Wtq = (unsigned short*)(ws + (64L << 20));
  unsigned short* Wtk = Wtq + 1024 * 1024;
  unsigned short* Wtv = Wtk + 1024 * 1024;
  unsigned short* SPb = (unsigned short*)ws;  // overlays xb

  // 1) x -> bf16
  cvt_kernel<<<2048, 256, 0, stream>>>(x, xb, 2097152L);

  // 2) W -> W^T bf16
  dim3 tb(32, 32);
  transposeW_kernel<<<dim3(32, 32), tb, 0, stream>>>(Wq, Wtq);
  transposeW_kernel<<<dim3(32, 32), tb, 0, stream>>>(Wk, Wtk);
  transposeW_kernel<<<dim3(32, 32), tb, 0, stream>>>(Wv, Wtv);

  // 3) Q = x@Wq + bq ; K = x@Wk + bk   (M=8192, N=1024, K=1024)
  bt_gemm<1, 0><<<dim3(8, 64, 1), 256, 0, stream>>>(
      xb, Wtq, bq, Qb, 8192, 1024, 1024, 1024, 1024, 1024, 0, 0, 0, 1.0f);
  bt_gemm<1, 0><<<dim3(8, 64, 1), 256, 0, stream>>>(
      xb, Wtk, bk, Kb, 8192, 1024, 1024, 1024, 1024, 1024, 0, 0, 0, 1.0f);

  // 4) V^T: Vt[e][s] = sum_d Wtv[e][d] * x_b[s][d] + bv[e]  (row-bias)
  bt_gemm<2, 0><<<dim3(16, 8, 4), 256, 0, stream>>>(
      Wtv, xb, bv, Vt, 1024, 2048, 1024, 1024, 1024, 2048,
      0, 2048L * 1024, 1024L * 2048, 1.0f);

  // 5) per-batch: scores -> softmax -> PV (fp32 out)
  for (int b = 0; b < 4; b++) {
    const long o2 = (long)b * 2048 * 1024;
    bt_gemm<0, 0><<<dim3(16, 16, 1), 256, 0, stream>>>(
        Qb + o2, Kb + o2, nullptr, SPb, 2048, 2048, 1024, 1024, 1024, 2048,
        0, 0, 0, 0.03125f);
    softmax_kernel<<<2048, 256, 0, stream>>>(SPb);
    bt_gemm<0, 1><<<dim3(8, 16, 1), 256, 0, stream>>>(
        SPb, Vt + o2, nullptr, (float*)out + o2, 2048, 1024, 2048, 2048, 2048,
        1024, 0, 0, 2048L * 1024, 1.0f);
  }
}

// Round 6
// 325.373 us; speedup vs baseline: 1.5229x; 1.5229x over previous
//
#include <hip/hip_runtime.h>
#include <stdint.h>

#define BK 32

typedef __attribute__((ext_vector_type(8))) short bf16x8;
typedef __attribute__((ext_vector_type(4))) float f32x4;

__device__ __forceinline__ unsigned short f2bf(float f) {
  unsigned int u = __builtin_bit_cast(unsigned int, f);
  u += 0x7fffu + ((u >> 16) & 1u);
  return (unsigned short)(u >> 16);
}
__device__ __forceinline__ float bf2f(unsigned short h) {
  unsigned int u = ((unsigned int)h) << 16;
  return __builtin_bit_cast(float, u);
}

__device__ __forceinline__ void gll16(const void* g, void* l) {
  __builtin_amdgcn_global_load_lds(
      (const __attribute__((address_space(1))) unsigned int*)g,
      (__attribute__((address_space(3))) unsigned int*)l, 16, 0, 0);
}

// ---------------------------------------------------------------------------
// bt-GEMM: C[M,N] = scale * (A[M,K] . B[N,K]^T) + bias
// BIASMODE: 0 = none, 1 = bias[col], 2 = bias[row]
// F32OUT:   0 = bf16 output, 1 = fp32 output
// m97 structure: 128x128 tile, BK=32, 4 waves (2x2), 4x4 16x16x32 frags,
// global_load_lds(16B) staging, 2 barriers per K-step.
// ---------------------------------------------------------------------------
template <int BIASMODE, int F32OUT>
__global__ __launch_bounds__(256) void bt_gemm(
    const unsigned short* __restrict__ A, const unsigned short* __restrict__ B,
    const float* __restrict__ bias, void* __restrict__ Cv,
    int M, int N, int K, int lda, int ldb, int ldc,
    long batchA, long batchB, long batchC, float scale) {
  __shared__ __align__(16) unsigned short As[128 * BK];
  __shared__ __align__(16) unsigned short Bs[128 * BK];

  const int z = blockIdx.z;
  A += (long)z * batchA;
  B += (long)z * batchB;

  const int tid = threadIdx.x;
  const int lane = tid & 63;
  const int wid = tid >> 6;
  const int wr = wid >> 1, wc = wid & 1;
  const int bm0 = blockIdx.y * 128;
  const int bn0 = blockIdx.x * 128;

  f32x4 zero = {0.f, 0.f, 0.f, 0.f};
  f32x4 acc[4][4];
#pragma unroll
  for (int m = 0; m < 4; m++)
#pragma unroll
    for (int n = 0; n < 4; n++) acc[m][n] = zero;

  const int nk = K / BK;
  for (int kt = 0; kt < nk; ++kt) {
    const int kk = kt * BK;
#pragma unroll
    for (int i = 0; i < 2; i++) {
      int c = tid + i * 256;  // 16B chunk id; lanes contiguous within wave
      int row = c >> 2, sub = c & 3;
      gll16(A + (size_t)(bm0 + row) * lda + kk + sub * 8, (void*)(As + c * 8));
      gll16(B + (size_t)(bn0 + row) * ldb + kk + sub * 8, (void*)(Bs + c * 8));
    }
    __syncthreads();  // drains vmcnt -> LDS tiles ready

    const int kq = (lane >> 4) * 8;
    bf16x8 af[4], bfr[4];
#pragma unroll
    for (int m = 0; m < 4; m++) {
      int r = wr * 64 + m * 16 + (lane & 15);
      af[m] = *(const bf16x8*)&As[r * BK + kq];
    }
#pragma unroll
    for (int n = 0; n < 4; n++) {
      int cidx = wc * 64 + n * 16 + (lane & 15);
      bfr[n] = *(const bf16x8*)&Bs[cidx * BK + kq];
    }
#pragma unroll
    for (int m = 0; m < 4; m++)
#pragma unroll
      for (int n = 0; n < 4; n++)
        acc[m][n] = __builtin_amdgcn_mfma_f32_16x16x32_bf16(af[m], bfr[n],
                                                            acc[m][n], 0, 0, 0);
    __syncthreads();  // protect LDS before next staging
  }

  // epilogue: C/D layout col=lane&15, row=(lane>>4)*4+j  [m89-verified]
  float* Cf = (float*)Cv + (F32OUT ? (long)z * batchC : 0);
  unsigned short* Cb = (unsigned short*)Cv + (F32OUT ? 0 : (long)z * batchC);
#pragma unroll
  for (int m = 0; m < 4; m++) {
    int row0 = bm0 + wr * 64 + m * 16 + ((lane >> 4) << 2);
#pragma unroll
    for (int n = 0; n < 4; n++) {
      int col = bn0 + wc * 64 + n * 16 + (lane & 15);
      f32x4 v = acc[m][n];
      float bc = (BIASMODE == 1) ? bias[col] : 0.0f;
#pragma unroll
      for (int j = 0; j < 4; j++) {
        float bj = (BIASMODE == 2) ? bias[row0 + j] : bc;
        float r = v[j] * scale + bj;
        if (F32OUT)
          Cf[(size_t)(row0 + j) * ldc + col] = r;
        else
          Cb[(size_t)(row0 + j) * ldc + col] = f2bf(r);
      }
    }
  }
}

// ---------------------------------------------------------------------------
// fp32 -> bf16 bulk convert (float4 in, 8B out)
// ---------------------------------------------------------------------------
__global__ __launch_bounds__(256) void cvt_kernel(const float* __restrict__ in,
                                                  unsigned short* __restrict__ out,
                                                  long n4) {
  long i = (long)blockIdx.x * blockDim.x + threadIdx.x;
  long stride = (long)gridDim.x * blockDim.x;
  for (; i < n4; i += stride) {
    float4 f = ((const float4*)in)[i];
    uint2 w;
    w.x = (unsigned int)f2bf(f.x) | ((unsigned int)f2bf(f.y) << 16);
    w.y = (unsigned int)f2bf(f.z) | ((unsigned int)f2bf(f.w) << 16);
    ((uint2*)out)[i] = w;
  }
}

// ---------------------------------------------------------------------------
// W [1024,1024] fp32 -> Wt [1024,1024] bf16 transposed (LDS tiled)
// ---------------------------------------------------------------------------
__global__ __launch_bounds__(1024) void transposeW_kernel(
    const float* __restrict__ W, unsigned short* __restrict__ Wt) {
  __shared__ float t[32][33];
  int x = threadIdx.x, y = threadIdx.y;
  int d = blockIdx.y * 32 + y, n = blockIdx.x * 32 + x;
  t[y][x] = W[(size_t)d * 1024 + n];
  __syncthreads();
  int nn = blockIdx.x * 32 + y, dd = blockIdx.y * 32 + x;
  Wt[(size_t)nn * 1024 + dd] = f2bf(t[x][y]);
}

// ---------------------------------------------------------------------------
// In-place row softmax over 2048 bf16. One 256-thread block per row.
// ---------------------------------------------------------------------------
__global__ __launch_bounds__(256) void softmax_kernel(unsigned short* __restrict__ SP) {
  const int row = blockIdx.x;
  unsigned short* rp = SP + (size_t)row * 2048;
  const int tid = threadIdx.x;
  const int wid = tid >> 6, lane = tid & 63;

  uint4 u = ((const uint4*)rp)[tid];  // 8 bf16
  float xv[8];
  xv[0] = bf2f(u.x & 0xffff); xv[1] = bf2f(u.x >> 16);
  xv[2] = bf2f(u.y & 0xffff); xv[3] = bf2f(u.y >> 16);
  xv[4] = bf2f(u.z & 0xffff); xv[5] = bf2f(u.z >> 16);
  xv[6] = bf2f(u.w & 0xffff); xv[7] = bf2f(u.w >> 16);

  float m = xv[0];
#pragma unroll
  for (int j = 1; j < 8; j++) m = fmaxf(m, xv[j]);
#pragma unroll
  for (int off = 32; off >= 1; off >>= 1) m = fmaxf(m, __shfl_xor(m, off));

  __shared__ float redm[4];
  __shared__ float reds[4];
  if (lane == 0) redm[wid] = m;
  __syncthreads();
  m = fmaxf(fmaxf(redm[0], redm[1]), fmaxf(redm[2], redm[3]));

  float p[8], s = 0.f;
#pragma unroll
  for (int j = 0; j < 8; j++) {
    p[j] = __expf(xv[j] - m);
    s += p[j];
  }
#pragma unroll
  for (int off = 32; off >= 1; off >>= 1) s += __shfl_xor(s, off);
  if (lane == 0) reds[wid] = s;
  __syncthreads();
  float inv = 1.0f / (reds[0] + reds[1] + reds[2] + reds[3]);

  uint4 o;
  o.x = (unsigned int)f2bf(p[0] * inv) | ((unsigned int)f2bf(p[1] * inv) << 16);
  o.y = (unsigned int)f2bf(p[2] * inv) | ((unsigned int)f2bf(p[3] * inv) << 16);
  o.z = (unsigned int)f2bf(p[4] * inv) | ((unsigned int)f2bf(p[5] * inv) << 16);
  o.w = (unsigned int)f2bf(p[6] * inv) | ((unsigned int)f2bf(p[7] * inv) << 16);
  ((uint4*)rp)[tid] = o;
}

// ---------------------------------------------------------------------------
extern "C" void kernel_launch(void* const* d_in, const int* in_sizes, int n_in,
                              void* d_out, int out_size, void* d_ws, size_t ws_size,
                              hipStream_t stream) {
  const float* x = (const float*)d_in[0];
  const float* Wq = (const float*)d_in[1];
  const float* bq = (const float*)d_in[2];
  const float* Wk = (const float*)d_in[3];
  const float* bk = (const float*)d_in[4];
  const float* Wv = (const float*)d_in[5];
  const float* bv = (const float*)d_in[6];
  float* out = (float*)d_out;  // fp32 (reference output dtype)

  // ws layout (102 MB — round-1-exercised footprint):
  //   [  0, 16) xb  : x bf16 [4][2048][1024]
  //   [ 16, 32) Kb  : K bf16
  //   [ 32, 48) Vt  : V^T bf16 [4][1024][2048]
  //   [ 48, 64) Qb  : Q bf16
  //   [ 64, 70) Wt q/k/v bf16 transposed
  //   [ 70,102) SP  : scores [4][2048][2048] bf16
  char* ws = (char*)d_ws;
  unsigned short* xb = (unsigned short*)ws;
  unsigned short* Kb = (unsigned short*)(ws + (16L << 20));
  unsigned short* Vt = (unsigned short*)(ws + (32L << 20));
  unsigned short* Qb = (unsigned short*)(ws + (48L << 20));
  unsigned short* Wtq = (unsigned short*)(ws + (64L << 20));
  unsigned short* Wtk = Wtq + 1024 * 1024;
  unsigned short* Wtv = Wtk + 1024 * 1024;
  unsigned short* SP = (unsigned short*)(ws + (70L << 20));

  // 1) x -> bf16
  cvt_kernel<<<2048, 256, 0, stream>>>(x, xb, 2097152L);

  // 2) W -> W^T bf16
  dim3 tb(32, 32);
  transposeW_kernel<<<dim3(32, 32), tb, 0, stream>>>(Wq, Wtq);
  transposeW_kernel<<<dim3(32, 32), tb, 0, stream>>>(Wk, Wtk);
  transposeW_kernel<<<dim3(32, 32), tb, 0, stream>>>(Wv, Wtv);

  // 3) Q = x@Wq + bq ; K = x@Wk + bk   (M=8192, N=1024, K=1024; 512 wgs)
  bt_gemm<1, 0><<<dim3(8, 64, 1), 256, 0, stream>>>(
      xb, Wtq, bq, Qb, 8192, 1024, 1024, 1024, 1024, 1024, 0, 0, 0, 1.0f);
  bt_gemm<1, 0><<<dim3(8, 64, 1), 256, 0, stream>>>(
      xb, Wtk, bk, Kb, 8192, 1024, 1024, 1024, 1024, 1024, 0, 0, 0, 1.0f);

  // 4) V^T: Vt[e][s] = sum_d Wtv[e][d] * x_b[s][d] + bv[e]  (512 wgs)
  bt_gemm<2, 0><<<dim3(16, 8, 4), 256, 0, stream>>>(
      Wtv, xb, bv, Vt, 1024, 2048, 1024, 1024, 1024, 2048,
      0, 2048L * 1024, 1024L * 2048, 1.0f);

  // 5) scores = Q.K^T / 32, all batches (1024 wgs = 4 blocks/CU)
  bt_gemm<0, 0><<<dim3(16, 16, 4), 256, 0, stream>>>(
      Qb, Kb, nullptr, SP, 2048, 2048, 1024, 1024, 1024, 2048,
      2048L * 1024, 2048L * 1024, 2048L * 2048, 0.03125f);

  // 6) softmax over all 8192 rows
  softmax_kernel<<<8192, 256, 0, stream>>>(SP);

  // 7) out = P.V, all batches (512 wgs)
  bt_gemm<0, 1><<<dim3(8, 16, 4), 256, 0, stream>>>(
      SP, Vt, nullptr, out, 2048, 1024, 2048, 2048, 2048, 1024,
      2048L * 2048, 1024L * 2048, 2048L * 1024, 1.0f);
}

// Round 7
// 285.693 us; speedup vs baseline: 1.7344x; 1.1389x over previous
//
#include <hip/hip_runtime.h>
#include <stdint.h>

typedef __attribute__((ext_vector_type(8))) short bf16x8;
typedef __attribute__((ext_vector_type(4))) float f32x4;

__device__ __forceinline__ unsigned short f2bf(float f) {
  unsigned int u = __builtin_bit_cast(unsigned int, f);
  u += 0x7fffu + ((u >> 16) & 1u);
  return (unsigned short)(u >> 16);
}
__device__ __forceinline__ float bf2f(unsigned short h) {
  unsigned int u = ((unsigned int)h) << 16;
  return __builtin_bit_cast(float, u);
}

__device__ __forceinline__ void gll16(const void* g, void* l) {
  __builtin_amdgcn_global_load_lds(
      (const __attribute__((address_space(1))) unsigned int*)g,
      (__attribute__((address_space(3))) unsigned int*)l, 16, 0, 0);
}

#define SB() __builtin_amdgcn_sched_barrier(0)
#define BAR() __builtin_amdgcn_s_barrier()
#define VMC6()                                     \
  asm volatile("s_waitcnt vmcnt(6)" ::: "memory"); \
  __builtin_amdgcn_sched_barrier(0)

// ---------------------------------------------------------------------------
// 256x256 8-phase bt-GEMM (T2 swizzle + T3/T4 counted vmcnt + T5 setprio).
// C[M,N] = scale*(A[M,K].B[N,K]^T)+bias.  K%128==0, M,N%256==0.
// 512 thr = 8 waves (2 wr x 4 wc); per-wave C = 128x64 (acc[8][4] f32x4).
// LDS 128KB dynamic: A[2dbuf][2half][128][64], B same at +64KB.
// K-tile = 64; iteration = 2 K-tiles = 8 phases; per phase: {ds_read subtile |
// stage 1 half-tile | barrier | MFMA quad | barrier}; vmcnt(6) at ph4/ph8
// keeps 3 half-tiles in flight across barriers (never drains).
// Chunk swizzle: 16B chunk index ch ^= (row&7) on BOTH gll-source and ds_read.
// BIASMODE: 0 none; 1 col-bias split at 1024 (bias1/bias2) for merged QK;
//           2 row-bias (bias1). F32OUT: 1 -> fp32 C.
// ---------------------------------------------------------------------------
__device__ __forceinline__ void stage2(const unsigned short* src, int ld,
                                       int rowbase, int kt, char* lds,
                                       int opofs, int dbuf, int half, int tid) {
#pragma unroll
  for (int i = 0; i < 2; i++) {
    int c = tid + i * 512;
    int r7 = c >> 3, ch = c & 7;
    int sch = ch ^ (r7 & 7);
    const char* g =
        (const char*)(src + (size_t)(rowbase + half * 128 + r7) * ld) +
        kt * 128 + sch * 16;
    gll16(g, lds + opofs + (dbuf * 2 + half) * 16384 + c * 16);
  }
}

__device__ __forceinline__ void ld_ahalf(const char* lds, int d, int mh, int wr,
                                         int lane, bf16x8 a[4][2]) {
#pragma unroll
  for (int m = 0; m < 4; m++)
#pragma unroll
    for (int kk = 0; kk < 2; kk++) {
      int r7 = wr * 64 + m * 16 + (lane & 15);
      int c = ((lane >> 4) + kk * 4) ^ (lane & 7);
      a[m][kk] =
          *(const bf16x8*)(lds + (d * 2 + mh) * 16384 + r7 * 128 + c * 16);
    }
}
__device__ __forceinline__ void ld_bhalf(const char* lds, int d, int nh, int wc,
                                         int lane, bf16x8 b[2][2]) {
#pragma unroll
  for (int n = 0; n < 2; n++)
#pragma unroll
    for (int kk = 0; kk < 2; kk++) {
      int r7 = wc * 32 + n * 16 + (lane & 15);
      int c = ((lane >> 4) + kk * 4) ^ (lane & 7);
      b[n][kk] = *(const bf16x8*)(lds + 65536 + (d * 2 + nh) * 16384 +
                                  r7 * 128 + c * 16);
    }
}

template <int MH, int NH>
__device__ __forceinline__ void mfma16(f32x4 acc[8][4], const bf16x8 a[4][2],
                                       const bf16x8 b[2][2]) {
  __builtin_amdgcn_s_setprio(1);
#pragma unroll
  for (int m = 0; m < 4; m++)
#pragma unroll
    for (int n = 0; n < 2; n++)
#pragma unroll
      for (int kk = 0; kk < 2; kk++)
        acc[MH * 4 + m][NH * 2 + n] = __builtin_amdgcn_mfma_f32_16x16x32_bf16(
            a[m][kk], b[n][kk], acc[MH * 4 + m][NH * 2 + n], 0, 0, 0);
  __builtin_amdgcn_s_setprio(0);
}

template <int BIASMODE, int F32OUT>
__global__ __launch_bounds__(512, 2) void gemm8(
    const unsigned short* __restrict__ A, const unsigned short* __restrict__ B,
    const float* __restrict__ bias1, const float* __restrict__ bias2,
    void* __restrict__ Cv, int K, int lda, int ldb, int ldc, long batchA,
    long batchB, long batchC, float scale) {
  extern __shared__ char lds[];
  const int z = blockIdx.z;
  A += (long)z * batchA;
  B += (long)z * batchB;

  // bijective XCD swizzle over the xy plane (nwg % 8 == 0 for all our grids)
  const int gx = gridDim.x;
  const int nwg = gx * gridDim.y;
  const int lin = blockIdx.y * gx + blockIdx.x;
  const int s = (lin & 7) * (nwg >> 3) + (lin >> 3);
  const int bn0 = (s % gx) * 256;
  const int bm0 = (s / gx) * 256;

  const int tid = threadIdx.x;
  const int lane = tid & 63;
  const int wid = tid >> 6;
  const int wr = wid >> 2, wc = wid & 3;

  f32x4 acc[8][4];
#pragma unroll
  for (int i = 0; i < 8; i++)
#pragma unroll
    for (int j = 0; j < 4; j++) acc[i][j] = (f32x4){0.f, 0.f, 0.f, 0.f};

  const int nkt = K >> 6;  // 64-wide K-tiles (even, since K%128==0)
  const int niter = nkt >> 1;

  // prologue: d0.{A0,B0,A1,B1}<-t0 ; d1.{A0,B0,A1}<-t1 (order matters: vmcnt)
  stage2(A, lda, bm0, 0, lds, 0, 0, 0, tid);
  stage2(B, ldb, bn0, 0, lds, 65536, 0, 0, tid);
  stage2(A, lda, bm0, 0, lds, 0, 0, 1, tid);
  stage2(B, ldb, bn0, 0, lds, 65536, 0, 1, tid);
  stage2(A, lda, bm0, 1, lds, 0, 1, 0, tid);
  stage2(B, ldb, bn0, 1, lds, 65536, 1, 0, tid);
  stage2(A, lda, bm0, 1, lds, 0, 1, 1, tid);
  VMC6();  // d0 fully arrived (3 half-tiles outstanding)
  BAR();

  bf16x8 a[2][4][2], b[2][2][2];
  for (int it = 0; it < niter; ++it) {
    const int t1 = 2 * it + 1;
    int t2 = 2 * it + 2;
    if (t2 >= nkt) t2 = nkt - 1;  // clamped redundant stage keeps vmcnt exact
    int t3 = 2 * it + 3;
    if (t3 >= nkt) t3 = nkt - 1;

    // ph1: read d0.A0,d0.B0 ; stage d1.B1<-t1 ; mfma(0,0)
    ld_ahalf(lds, 0, 0, wr, lane, a[0]);
    ld_bhalf(lds, 0, 0, wc, lane, b[0]);
    stage2(B, ldb, bn0, t1, lds, 65536, 1, 1, tid);
    SB();
    BAR();
    mfma16<0, 0>(acc, a[0], b[0]);
    SB();
    BAR();
    // ph2: read d0.A1 ; stage d0.A0<-t2 ; mfma(1,0)
    ld_ahalf(lds, 0, 1, wr, lane, a[1]);
    stage2(A, lda, bm0, t2, lds, 0, 0, 0, tid);
    SB();
    BAR();
    mfma16<1, 0>(acc, a[1], b[0]);
    SB();
    BAR();
    // ph3: read d0.B1 ; stage d0.B0<-t2 ; mfma(0,1)
    ld_bhalf(lds, 0, 1, wc, lane, b[1]);
    stage2(B, ldb, bn0, t2, lds, 65536, 0, 0, tid);
    SB();
    BAR();
    mfma16<0, 1>(acc, a[0], b[1]);
    SB();
    BAR();
    // ph4: stage d0.A1<-t2 ; vmcnt(6) ; mfma(1,1)
    stage2(A, lda, bm0, t2, lds, 0, 0, 1, tid);
    VMC6();
    BAR();
    mfma16<1, 1>(acc, a[1], b[1]);
    SB();
    BAR();
    // ph5: read d1.A0,d1.B0 ; stage d0.B1<-t2 ; mfma(0,0)
    ld_ahalf(lds, 1, 0, wr, lane, a[0]);
    ld_bhalf(lds, 1, 0, wc, lane, b[0]);
    stage2(B, ldb, bn0, t2, lds, 65536, 0, 1, tid);
    SB();
    BAR();
    mfma16<0, 0>(acc, a[0], b[0]);
    SB();
    BAR();
    // ph6: read d1.A1 ; stage d1.A0<-t3 ; mfma(1,0)
    ld_ahalf(lds, 1, 1, wr, lane, a[1]);
    stage2(A, lda, bm0, t3, lds, 0, 1, 0, tid);
    SB();
    BAR();
    mfma16<1, 0>(acc, a[1], b[0]);
    SB();
    BAR();
    // ph7: read d1.B1 ; stage d1.B0<-t3 ; mfma(0,1)
    ld_bhalf(lds, 1, 1, wc, lane, b[1]);
    stage2(B, ldb, bn0, t3, lds, 65536, 1, 0, tid);
    SB();
    BAR();
    mfma16<0, 1>(acc, a[0], b[1]);
    SB();
    BAR();
    // ph8: stage d1.A1<-t3 ; vmcnt(6) ; mfma(1,1)
    stage2(A, lda, bm0, t3, lds, 0, 1, 1, tid);
    VMC6();
    BAR();
    mfma16<1, 1>(acc, a[1], b[1]);
    SB();
    BAR();
  }

  // epilogue: C/D frag layout col=lane&15, row=(lane>>4)*4+j [m89]
  const int r4 = (lane >> 4) << 2;
  const int c0 = lane & 15;
  float* Cf = (float*)Cv + (F32OUT ? (long)z * batchC : 0);
  unsigned short* Cb = (unsigned short*)Cv + (F32OUT ? 0 : (long)z * batchC);
#pragma unroll
  for (int am = 0; am < 8; am++) {
    int row = bm0 + (am >> 2) * 128 + wr * 64 + (am & 3) * 16 + r4;
#pragma unroll
    for (int an = 0; an < 4; an++) {
      int col = bn0 + (an >> 1) * 128 + wc * 32 + (an & 1) * 16 + c0;
      float bc = 0.f;
      if (BIASMODE == 1) bc = (col < 1024) ? bias1[col] : bias2[col - 1024];
      f32x4 v = acc[am][an];
#pragma unroll
      for (int j = 0; j < 4; j++) {
        float bj = (BIASMODE == 2) ? bias1[row + j] : bc;
        float r = v[j] * scale + bj;
        if (F32OUT)
          Cf[(size_t)(row + j) * ldc + col] = r;
        else
          Cb[(size_t)(row + j) * ldc + col] = f2bf(r);
      }
    }
  }
}

// ---------------------------------------------------------------------------
__global__ __launch_bounds__(256) void cvt_kernel(const float* __restrict__ in,
                                                  unsigned short* __restrict__ out,
                                                  long n4) {
  long i = (long)blockIdx.x * blockDim.x + threadIdx.x;
  long stride = (long)gridDim.x * blockDim.x;
  for (; i < n4; i += stride) {
    float4 f = ((const float4*)in)[i];
    uint2 w;
    w.x = (unsigned int)f2bf(f.x) | ((unsigned int)f2bf(f.y) << 16);
    w.y = (unsigned int)f2bf(f.z) | ((unsigned int)f2bf(f.w) << 16);
    ((uint2*)out)[i] = w;
  }
}

// ---------------------------------------------------------------------------
__global__ __launch_bounds__(1024) void transposeW_kernel(
    const float* __restrict__ W, unsigned short* __restrict__ Wt) {
  __shared__ float t[32][33];
  int x = threadIdx.x, y = threadIdx.y;
  int d = blockIdx.y * 32 + y, n = blockIdx.x * 32 + x;
  t[y][x] = W[(size_t)d * 1024 + n];
  __syncthreads();
  int nn = blockIdx.x * 32 + y, dd = blockIdx.y * 32 + x;
  Wt[(size_t)nn * 1024 + dd] = f2bf(t[x][y]);
}

// ---------------------------------------------------------------------------
__global__ __launch_bounds__(256) void softmax_kernel(unsigned short* __restrict__ SP) {
  const int row = blockIdx.x;
  unsigned short* rp = SP + (size_t)row * 2048;
  const int tid = threadIdx.x;
  const int wid = tid >> 6, lane = tid & 63;

  uint4 u = ((const uint4*)rp)[tid];  // 8 bf16
  float xv[8];
  xv[0] = bf2f(u.x & 0xffff); xv[1] = bf2f(u.x >> 16);
  xv[2] = bf2f(u.y & 0xffff); xv[3] = bf2f(u.y >> 16);
  xv[4] = bf2f(u.z & 0xffff); xv[5] = bf2f(u.z >> 16);
  xv[6] = bf2f(u.w & 0xffff); xv[7] = bf2f(u.w >> 16);

  float m = xv[0];
#pragma unroll
  for (int j = 1; j < 8; j++) m = fmaxf(m, xv[j]);
#pragma unroll
  for (int off = 32; off >= 1; off >>= 1) m = fmaxf(m, __shfl_xor(m, off));

  __shared__ float redm[4];
  __shared__ float reds[4];
  if (lane == 0) redm[wid] = m;
  __syncthreads();
  m = fmaxf(fmaxf(redm[0], redm[1]), fmaxf(redm[2], redm[3]));

  float p[8], sm = 0.f;
#pragma unroll
  for (int j = 0; j < 8; j++) {
    p[j] = __expf(xv[j] - m);
    sm += p[j];
  }
#pragma unroll
  for (int off = 32; off >= 1; off >>= 1) sm += __shfl_xor(sm, off);
  if (lane == 0) reds[wid] = sm;
  __syncthreads();
  float inv = 1.0f / (reds[0] + reds[1] + reds[2] + reds[3]);

  uint4 o;
  o.x = (unsigned int)f2bf(p[0] * inv) | ((unsigned int)f2bf(p[1] * inv) << 16);
  o.y = (unsigned int)f2bf(p[2] * inv) | ((unsigned int)f2bf(p[3] * inv) << 16);
  o.z = (unsigned int)f2bf(p[4] * inv) | ((unsigned int)f2bf(p[5] * inv) << 16);
  o.w = (unsigned int)f2bf(p[6] * inv) | ((unsigned int)f2bf(p[7] * inv) << 16);
  ((uint4*)rp)[tid] = o;
}

// ---------------------------------------------------------------------------
extern "C" void kernel_launch(void* const* d_in, const int* in_sizes, int n_in,
                              void* d_out, int out_size, void* d_ws, size_t ws_size,
                              hipStream_t stream) {
  const float* x = (const float*)d_in[0];
  const float* Wq = (const float*)d_in[1];
  const float* bq = (const float*)d_in[2];
  const float* Wk = (const float*)d_in[3];
  const float* bk = (const float*)d_in[4];
  const float* Wv = (const float*)d_in[5];
  const float* bv = (const float*)d_in[6];
  float* out = (float*)d_out;  // fp32 (reference output dtype)

  // ws layout (102 MB, round-1-exercised):
  //   [  0, 16) xb  : x bf16 [4][2048][1024]
  //   [ 16, 48) QKb : [8192][2048] bf16; cols 0-1023 = Q, 1024-2047 = K
  //   [ 48, 64) Vt  : V^T bf16 [1024 e][8192 s] (per-batch cols 2048b..+2047)
  //   [ 64, 96) SP  : scores [4][2048][2048] bf16
  //   [ 96,102) Wt  : Wtq|Wtk|Wtv bf16 transposed (contiguous: QK B-operand)
  char* ws = (char*)d_ws;
  unsigned short* xb = (unsigned short*)ws;
  unsigned short* QKb = (unsigned short*)(ws + (16L << 20));
  unsigned short* Vt = (unsigned short*)(ws + (48L << 20));
  unsigned short* SP = (unsigned short*)(ws + (64L << 20));
  unsigned short* Wtq = (unsigned short*)(ws + (96L << 20));
  unsigned short* Wtk = Wtq + 1024 * 1024;
  unsigned short* Wtv = Wtk + 1024 * 1024;

  const int LDS8 = 131072;
  (void)hipFuncSetAttribute(reinterpret_cast<const void*>(&gemm8<1, 0>),
                            hipFuncAttributeMaxDynamicSharedMemorySize, LDS8);
  (void)hipFuncSetAttribute(reinterpret_cast<const void*>(&gemm8<2, 0>),
                            hipFuncAttributeMaxDynamicSharedMemorySize, LDS8);
  (void)hipFuncSetAttribute(reinterpret_cast<const void*>(&gemm8<0, 0>),
                            hipFuncAttributeMaxDynamicSharedMemorySize, LDS8);
  (void)hipFuncSetAttribute(reinterpret_cast<const void*>(&gemm8<0, 1>),
                            hipFuncAttributeMaxDynamicSharedMemorySize, LDS8);

  // 1) x -> bf16
  cvt_kernel<<<2048, 256, 0, stream>>>(x, xb, 2097152L);

  // 2) W -> W^T bf16 (Wtq,Wtk contiguous => QK merged B-operand)
  dim3 tb(32, 32);
  transposeW_kernel<<<dim3(32, 32), tb, 0, stream>>>(Wq, Wtq);
  transposeW_kernel<<<dim3(32, 32), tb, 0, stream>>>(Wk, Wtk);
  transposeW_kernel<<<dim3(32, 32), tb, 0, stream>>>(Wv, Wtv);

  // 3) merged QK: [8192][2048] = xb @ [Wtq;Wtk]^T + [bq|bk]  (256 wgs)
  gemm8<1, 0><<<dim3(8, 32, 1), 512, LDS8, stream>>>(
      xb, Wtq, bq, bk, QKb, 1024, 1024, 1024, 2048, 0, 0, 0, 1.0f);

  // 4) V^T direct: Vt[e][s] = sum_d Wtv[e][d]*x[s][d] + bv[e]  (128 wgs)
  gemm8<2, 0><<<dim3(32, 4, 1), 512, LDS8, stream>>>(
      Wtv, xb, bv, nullptr, Vt, 1024, 1024, 1024, 8192, 0, 0, 0, 1.0f);

  // 5) scores = Q.K^T/32 (A=QKb Q-cols, B=QKb K-cols; 256 wgs)
  gemm8<0, 0><<<dim3(8, 8, 4), 512, LDS8, stream>>>(
      QKb, QKb + 1024, nullptr, nullptr, SP, 1024, 2048, 2048, 2048,
      2048L * 2048, 2048L * 2048, 2048L * 2048, 0.03125f);

  // 6) softmax over all 8192 rows
  softmax_kernel<<<8192, 256, 0, stream>>>(SP);

  // 7) out = P.V  (B=Vt, ldb=8192, per-batch col offset 2048; 128 wgs)
  gemm8<0, 1><<<dim3(4, 8, 4), 512, LDS8, stream>>>(
      SP, Vt, nullptr, nullptr, out, 2048, 2048, 8192, 1024, 2048L * 2048,
      2048L, 2048L * 1024, 1.0f);
}

// Round 8
// 285.627 us; speedup vs baseline: 1.7348x; 1.0002x over previous
//
#include <hip/hip_runtime.h>
#include <stdint.h>

typedef __attribute__((ext_vector_type(8))) short bf16x8;
typedef __attribute__((ext_vector_type(4))) float f32x4;

__device__ __forceinline__ unsigned short f2bf(float f) {
  unsigned int u = __builtin_bit_cast(unsigned int, f);
  u += 0x7fffu + ((u >> 16) & 1u);
  return (unsigned short)(u >> 16);
}
__device__ __forceinline__ float bf2f(unsigned short h) {
  unsigned int u = ((unsigned int)h) << 16;
  return __builtin_bit_cast(float, u);
}

__device__ __forceinline__ void gll16(const void* g, void* l) {
  __builtin_amdgcn_global_load_lds(
      (const __attribute__((address_space(1))) unsigned int*)g,
      (__attribute__((address_space(3))) unsigned int*)l, 16, 0, 0);
}

// HW barrier + COMPILER memory fence (no waitcnt drain — that's the point).
#define BARF() asm volatile("s_barrier" ::: "memory")
// counted vmcnt: 6 gll (=3 half-tiles) may stay in flight across the barrier
#define VMC6() asm volatile("s_waitcnt vmcnt(6)" ::: "memory")

// ---------------------------------------------------------------------------
// 256x256 8-phase bt-GEMM (T2 swizzle + T3/T4 counted vmcnt + T5 setprio).
// C[M,N] = scale*(A[M,K].B[N,K]^T)+bias.  K%128==0, M,N%256==0.
// 512 thr = 8 waves (2 wr x 4 wc); per-wave C = 128x64 (acc[8][4] f32x4).
// LDS 128KB dynamic: A[2dbuf][2half][128][64], B same at +64KB.
// Per phase: {ds_read subtile | stage 1 half-tile | s_barrier(mem-fence) |
// MFMA quad (compiler inserts exact lgkmcnt waits) | s_barrier}; vmcnt(6) at
// ph4/ph8 only. NO sched_barrier(0) — plain-load deps are compiler-tracked;
// order-pinning measured -40% class (m141).
// Chunk swizzle: 16B chunk index ch ^= (row&7) on BOTH gll-source and ds_read.
// ---------------------------------------------------------------------------
__device__ __forceinline__ void stage2(const unsigned short* src, int ld,
                                       int rowbase, int kt, char* lds,
                                       int opofs, int dbuf, int half, int tid) {
#pragma unroll
  for (int i = 0; i < 2; i++) {
    int c = tid + i * 512;
    int r7 = c >> 3, ch = c & 7;
    int sch = ch ^ (r7 & 7);
    const char* g =
        (const char*)(src + (size_t)(rowbase + half * 128 + r7) * ld) +
        kt * 128 + sch * 16;
    gll16(g, lds + opofs + (dbuf * 2 + half) * 16384 + c * 16);
  }
}

__device__ __forceinline__ void ld_ahalf(const char* lds, int d, int mh, int wr,
                                         int lane, bf16x8 a[4][2]) {
#pragma unroll
  for (int m = 0; m < 4; m++)
#pragma unroll
    for (int kk = 0; kk < 2; kk++) {
      int r7 = wr * 64 + m * 16 + (lane & 15);
      int c = ((lane >> 4) + kk * 4) ^ (lane & 7);
      a[m][kk] =
          *(const bf16x8*)(lds + (d * 2 + mh) * 16384 + r7 * 128 + c * 16);
    }
}
__device__ __forceinline__ void ld_bhalf(const char* lds, int d, int nh, int wc,
                                         int lane, bf16x8 b[2][2]) {
#pragma unroll
  for (int n = 0; n < 2; n++)
#pragma unroll
    for (int kk = 0; kk < 2; kk++) {
      int r7 = wc * 32 + n * 16 + (lane & 15);
      int c = ((lane >> 4) + kk * 4) ^ (lane & 7);
      b[n][kk] = *(const bf16x8*)(lds + 65536 + (d * 2 + nh) * 16384 +
                                  r7 * 128 + c * 16);
    }
}

template <int MH, int NH>
__device__ __forceinline__ void mfma16(f32x4 acc[8][4], const bf16x8 a[4][2],
                                       const bf16x8 b[2][2]) {
  __builtin_amdgcn_s_setprio(1);
#pragma unroll
  for (int m = 0; m < 4; m++)
#pragma unroll
    for (int n = 0; n < 2; n++)
#pragma unroll
      for (int kk = 0; kk < 2; kk++)
        acc[MH * 4 + m][NH * 2 + n] = __builtin_amdgcn_mfma_f32_16x16x32_bf16(
            a[m][kk], b[n][kk], acc[MH * 4 + m][NH * 2 + n], 0, 0, 0);
  __builtin_amdgcn_s_setprio(0);
}

template <int BIASMODE, int F32OUT>
__global__ __launch_bounds__(512, 2) void gemm8(
    const unsigned short* __restrict__ A, const unsigned short* __restrict__ B,
    const float* __restrict__ bias1, const float* __restrict__ bias2,
    void* __restrict__ Cv, int K, int lda, int ldb, int ldc, long batchA,
    long batchB, long batchC, float scale) {
  extern __shared__ char lds[];
  const int z = blockIdx.z;
  A += (long)z * batchA;
  B += (long)z * batchB;

  // bijective XCD swizzle over the xy plane (nwg % 8 == 0 for all our grids)
  const int gx = gridDim.x;
  const int nwg = gx * gridDim.y;
  const int lin = blockIdx.y * gx + blockIdx.x;
  const int s = (lin & 7) * (nwg >> 3) + (lin >> 3);
  const int bn0 = (s % gx) * 256;
  const int bm0 = (s / gx) * 256;

  const int tid = threadIdx.x;
  const int lane = tid & 63;
  const int wid = tid >> 6;
  const int wr = wid >> 2, wc = wid & 3;

  f32x4 acc[8][4];
#pragma unroll
  for (int i = 0; i < 8; i++)
#pragma unroll
    for (int j = 0; j < 4; j++) acc[i][j] = (f32x4){0.f, 0.f, 0.f, 0.f};

  const int nkt = K >> 6;  // 64-wide K-tiles (even, since K%128==0)
  const int niter = nkt >> 1;

  // prologue: d0.{A0,B0,A1,B1}<-t0 ; d1.{A0,B0,A1}<-t1 (issue order = vmcnt)
  stage2(A, lda, bm0, 0, lds, 0, 0, 0, tid);
  stage2(B, ldb, bn0, 0, lds, 65536, 0, 0, tid);
  stage2(A, lda, bm0, 0, lds, 0, 0, 1, tid);
  stage2(B, ldb, bn0, 0, lds, 65536, 0, 1, tid);
  stage2(A, lda, bm0, 1, lds, 0, 1, 0, tid);
  stage2(B, ldb, bn0, 1, lds, 65536, 1, 0, tid);
  stage2(A, lda, bm0, 1, lds, 0, 1, 1, tid);
  VMC6();  // d0 fully arrived (14 issued, wait->8 done; 3 half-tiles in flight)
  BARF();

  bf16x8 a[2][4][2], b[2][2][2];
  for (int it = 0; it < niter; ++it) {
    const int t1 = 2 * it + 1;
    int t2 = 2 * it + 2;
    if (t2 >= nkt) t2 = nkt - 1;  // clamped redundant stage keeps vmcnt exact
    int t3 = 2 * it + 3;
    if (t3 >= nkt) t3 = nkt - 1;

    // ph1: read d0.A0,d0.B0 ; stage d1.B1<-t1 ; mfma(0,0)
    ld_ahalf(lds, 0, 0, wr, lane, a[0]);
    ld_bhalf(lds, 0, 0, wc, lane, b[0]);
    stage2(B, ldb, bn0, t1, lds, 65536, 1, 1, tid);
    BARF();
    mfma16<0, 0>(acc, a[0], b[0]);
    BARF();
    // ph2: read d0.A1 ; stage d0.A0<-t2 ; mfma(1,0)
    ld_ahalf(lds, 0, 1, wr, lane, a[1]);
    stage2(A, lda, bm0, t2, lds, 0, 0, 0, tid);
    BARF();
    mfma16<1, 0>(acc, a[1], b[0]);
    BARF();
    // ph3: read d0.B1 ; stage d0.B0<-t2 ; mfma(0,1)
    ld_bhalf(lds, 0, 1, wc, lane, b[1]);
    stage2(B, ldb, bn0, t2, lds, 65536, 0, 0, tid);
    BARF();
    mfma16<0, 1>(acc, a[0], b[1]);
    BARF();
    // ph4: stage d0.A1<-t2 ; vmcnt(6) ; mfma(1,1)   [d1 now fully arrived]
    stage2(A, lda, bm0, t2, lds, 0, 0, 1, tid);
    VMC6();
    BARF();
    mfma16<1, 1>(acc, a[1], b[1]);
    BARF();
    // ph5: read d1.A0,d1.B0 ; stage d0.B1<-t2 ; mfma(0,0)
    ld_ahalf(lds, 1, 0, wr, lane, a[0]);
    ld_bhalf(lds, 1, 0, wc, lane, b[0]);
    stage2(B, ldb, bn0, t2, lds, 65536, 0, 1, tid);
    BARF();
    mfma16<0, 0>(acc, a[0], b[0]);
    BARF();
    // ph6: read d1.A1 ; stage d1.A0<-t3 ; mfma(1,0)
    ld_ahalf(lds, 1, 1, wr, lane, a[1]);
    stage2(A, lda, bm0, t3, lds, 0, 1, 0, tid);
    BARF();
    mfma16<1, 0>(acc, a[1], b[0]);
    BARF();
    // ph7: read d1.B1 ; stage d1.B0<-t3 ; mfma(0,1)
    ld_bhalf(lds, 1, 1, wc, lane, b[1]);
    stage2(B, ldb, bn0, t3, lds, 65536, 1, 0, tid);
    BARF();
    mfma16<0, 1>(acc, a[0], b[1]);
    BARF();
    // ph8: stage d1.A1<-t3 ; vmcnt(6) ; mfma(1,1)   [d0<-t2 fully arrived]
    stage2(A, lda, bm0, t3, lds, 0, 1, 1, tid);
    VMC6();
    BARF();
    mfma16<1, 1>(acc, a[1], b[1]);
    BARF();
  }

  // epilogue: C/D frag layout col=lane&15, row=(lane>>4)*4+j [m89]
  const int r4 = (lane >> 4) << 2;
  const int c0 = lane & 15;
  float* Cf = (float*)Cv + (F32OUT ? (long)z * batchC : 0);
  unsigned short* Cb = (unsigned short*)Cv + (F32OUT ? 0 : (long)z * batchC);
#pragma unroll
  for (int am = 0; am < 8; am++) {
    int row = bm0 + (am >> 2) * 128 + wr * 64 + (am & 3) * 16 + r4;
#pragma unroll
    for (int an = 0; an < 4; an++) {
      int col = bn0 + (an >> 1) * 128 + wc * 32 + (an & 1) * 16 + c0;
      float bc = 0.f;
      if (BIASMODE == 1) bc = (col < 1024) ? bias1[col] : bias2[col - 1024];
      f32x4 v = acc[am][an];
#pragma unroll
      for (int j = 0; j < 4; j++) {
        float bj = (BIASMODE == 2) ? bias1[row + j] : bc;
        float r = v[j] * scale + bj;
        if (F32OUT)
          Cf[(size_t)(row + j) * ldc + col] = r;
        else
          Cb[(size_t)(row + j) * ldc + col] = f2bf(r);
      }
    }
  }
}

// ---------------------------------------------------------------------------
__global__ __launch_bounds__(256) void cvt_kernel(const float* __restrict__ in,
                                                  unsigned short* __restrict__ out,
                                                  long n4) {
  long i = (long)blockIdx.x * blockDim.x + threadIdx.x;
  long stride = (long)gridDim.x * blockDim.x;
  for (; i < n4; i += stride) {
    float4 f = ((const float4*)in)[i];
    uint2 w;
    w.x = (unsigned int)f2bf(f.x) | ((unsigned int)f2bf(f.y) << 16);
    w.y = (unsigned int)f2bf(f.z) | ((unsigned int)f2bf(f.w) << 16);
    ((uint2*)out)[i] = w;
  }
}

// ---------------------------------------------------------------------------
__global__ __launch_bounds__(1024) void transposeW_kernel(
    const float* __restrict__ W, unsigned short* __restrict__ Wt) {
  __shared__ float t[32][33];
  int x = threadIdx.x, y = threadIdx.y;
  int d = blockIdx.y * 32 + y, n = blockIdx.x * 32 + x;
  t[y][x] = W[(size_t)d * 1024 + n];
  __syncthreads();
  int nn = blockIdx.x * 32 + y, dd = blockIdx.y * 32 + x;
  Wt[(size_t)nn * 1024 + dd] = f2bf(t[x][y]);
}

// ---------------------------------------------------------------------------
__global__ __launch_bounds__(256) void softmax_kernel(unsigned short* __restrict__ SP) {
  const int row = blockIdx.x;
  unsigned short* rp = SP + (size_t)row * 2048;
  const int tid = threadIdx.x;
  const int wid = tid >> 6, lane = tid & 63;

  uint4 u = ((const uint4*)rp)[tid];  // 8 bf16
  float xv[8];
  xv[0] = bf2f(u.x & 0xffff); xv[1] = bf2f(u.x >> 16);
  xv[2] = bf2f(u.y & 0xffff); xv[3] = bf2f(u.y >> 16);
  xv[4] = bf2f(u.z & 0xffff); xv[5] = bf2f(u.z >> 16);
  xv[6] = bf2f(u.w & 0xffff); xv[7] = bf2f(u.w >> 16);

  float m = xv[0];
#pragma unroll
  for (int j = 1; j < 8; j++) m = fmaxf(m, xv[j]);
#pragma unroll
  for (int off = 32; off >= 1; off >>= 1) m = fmaxf(m, __shfl_xor(m, off));

  __shared__ float redm[4];
  __shared__ float reds[4];
  if (lane == 0) redm[wid] = m;
  __syncthreads();
  m = fmaxf(fmaxf(redm[0], redm[1]), fmaxf(redm[2], redm[3]));

  float p[8], sm = 0.f;
#pragma unroll
  for (int j = 0; j < 8; j++) {
    p[j] = __expf(xv[j] - m);
    sm += p[j];
  }
#pragma unroll
  for (int off = 32; off >= 1; off >>= 1) sm += __shfl_xor(sm, off);
  if (lane == 0) reds[wid] = sm;
  __syncthreads();
  float inv = 1.0f / (reds[0] + reds[1] + reds[2] + reds[3]);

  uint4 o;
  o.x = (unsigned int)f2bf(p[0] * inv) | ((unsigned int)f2bf(p[1] * inv) << 16);
  o.y = (unsigned int)f2bf(p[2] * inv) | ((unsigned int)f2bf(p[3] * inv) << 16);
  o.z = (unsigned int)f2bf(p[4] * inv) | ((unsigned int)f2bf(p[5] * inv) << 16);
  o.w = (unsigned int)f2bf(p[6] * inv) | ((unsigned int)f2bf(p[7] * inv) << 16);
  ((uint4*)rp)[tid] = o;
}

// ---------------------------------------------------------------------------
extern "C" void kernel_launch(void* const* d_in, const int* in_sizes, int n_in,
                              void* d_out, int out_size, void* d_ws, size_t ws_size,
                              hipStream_t stream) {
  const float* x = (const float*)d_in[0];
  const float* Wq = (const float*)d_in[1];
  const float* bq = (const float*)d_in[2];
  const float* Wk = (const float*)d_in[3];
  const float* bk = (const float*)d_in[4];
  const float* Wv = (const float*)d_in[5];
  const float* bv = (const float*)d_in[6];
  float* out = (float*)d_out;  // fp32 (reference output dtype)

  // ws layout (102 MB, round-1-exercised):
  //   [  0, 16) xb  : x bf16 [4][2048][1024]
  //   [ 16, 48) QKb : [8192][2048] bf16; cols 0-1023 = Q, 1024-2047 = K
  //   [ 48, 64) Vt  : V^T bf16 [1024 e][8192 s] (per-batch cols 2048b..+2047)
  //   [ 64, 96) SP  : scores [4][2048][2048] bf16
  //   [ 96,102) Wt  : Wtq|Wtk|Wtv bf16 transposed (contiguous: QK B-operand)
  char* ws = (char*)d_ws;
  unsigned short* xb = (unsigned short*)ws;
  unsigned short* QKb = (unsigned short*)(ws + (16L << 20));
  unsigned short* Vt = (unsigned short*)(ws + (48L << 20));
  unsigned short* SP = (unsigned short*)(ws + (64L << 20));
  unsigned short* Wtq = (unsigned short*)(ws + (96L << 20));
  unsigned short* Wtk = Wtq + 1024 * 1024;
  unsigned short* Wtv = Wtk + 1024 * 1024;

  const int LDS8 = 131072;
  (void)hipFuncSetAttribute(reinterpret_cast<const void*>(&gemm8<1, 0>),
                            hipFuncAttributeMaxDynamicSharedMemorySize, LDS8);
  (void)hipFuncSetAttribute(reinterpret_cast<const void*>(&gemm8<2, 0>),
                            hipFuncAttributeMaxDynamicSharedMemorySize, LDS8);
  (void)hipFuncSetAttribute(reinterpret_cast<const void*>(&gemm8<0, 0>),
                            hipFuncAttributeMaxDynamicSharedMemorySize, LDS8);
  (void)hipFuncSetAttribute(reinterpret_cast<const void*>(&gemm8<0, 1>),
                            hipFuncAttributeMaxDynamicSharedMemorySize, LDS8);

  // 1) x -> bf16
  cvt_kernel<<<2048, 256, 0, stream>>>(x, xb, 2097152L);

  // 2) W -> W^T bf16 (Wtq,Wtk contiguous => QK merged B-operand)
  dim3 tb(32, 32);
  transposeW_kernel<<<dim3(32, 32), tb, 0, stream>>>(Wq, Wtq);
  transposeW_kernel<<<dim3(32, 32), tb, 0, stream>>>(Wk, Wtk);
  transposeW_kernel<<<dim3(32, 32), tb, 0, stream>>>(Wv, Wtv);

  // 3) merged QK: [8192][2048] = xb @ [Wtq;Wtk]^T + [bq|bk]  (256 wgs)
  gemm8<1, 0><<<dim3(8, 32, 1), 512, LDS8, stream>>>(
      xb, Wtq, bq, bk, QKb, 1024, 1024, 1024, 2048, 0, 0, 0, 1.0f);

  // 4) V^T direct: Vt[e][s] = sum_d Wtv[e][d]*x[s][d] + bv[e]  (128 wgs)
  gemm8<2, 0><<<dim3(32, 4, 1), 512, LDS8, stream>>>(
      Wtv, xb, bv, nullptr, Vt, 1024, 1024, 1024, 8192, 0, 0, 0, 1.0f);

  // 5) scores = Q.K^T/32 (A=QKb Q-cols, B=QKb K-cols; 256 wgs)
  gemm8<0, 0><<<dim3(8, 8, 4), 512, LDS8, stream>>>(
      QKb, QKb + 1024, nullptr, nullptr, SP, 1024, 2048, 2048, 2048,
      2048L * 2048, 2048L * 2048, 2048L * 2048, 0.03125f);

  // 6) softmax over all 8192 rows
  softmax_kernel<<<8192, 256, 0, stream>>>(SP);

  // 7) out = P.V  (B=Vt, ldb=8192, per-batch col offset 2048; 128 wgs)
  gemm8<0, 1><<<dim3(4, 8, 4), 512, LDS8, stream>>>(
      SP, Vt, nullptr, nullptr, out, 2048, 2048, 8192, 1024, 2048L * 2048,
      2048L, 2048L * 1024, 1.0f);
}